// Round 21
// baseline (121.922 us; speedup 1.0000x reference)
//
#include <hip/hip_runtime.h>

#define N_NODES 100000
#define IN_F    256
#define OUT_F   256
#define BATCH   50000
#define NSAMP   25
#define K2      512
#define NTILE_N 1563    // neigh half: ceil(100000/64), per-node
#define NTILE_B 782     // self half:  ceil(50000/64), per-batch-row
#define NTILE_T (NTILE_N + NTILE_B)   // 2345 unified tiles
#define NBLK    512     // persistent blocks (2 per CU)

typedef _Float16 f16_t;
typedef f16_t f16x8 __attribute__((ext_vector_type(8)));
typedef float f32x4 __attribute__((ext_vector_type(4)));
typedef float f32x2 __attribute__((ext_vector_type(2)));
typedef __bf16 bf16_t;
typedef bf16_t bf16x8 __attribute__((ext_vector_type(8)));

#if defined(__has_builtin)
#if __has_builtin(__builtin_amdgcn_cvt_pk_f32_fp8) && __has_builtin(__builtin_amdgcn_cvt_pk_fp8_f32)
#define FP8_HW 1
#endif
#endif
#ifndef FP8_HW
#include <hip/hip_fp8.h>
#endif

// workspace (bytes): Pselfb f16 [50000][256] (batch-indexed), P8 fp8 [100000][256], Wg f16 [512][256]
#define P8_OFF   25600000L
#define WG_OFF   51200000L
#define WS_NEED  (WG_OFF + 512L * 256 * 2)

__device__ __forceinline__ float h2f(unsigned short u) {
    union { unsigned short u; f16_t h; } t; t.u = u; return (float)t.h;
}

__device__ __forceinline__ unsigned int pk_fp8x4(float a, float b, float c, float d) {
#ifdef FP8_HW
    unsigned int r = __builtin_amdgcn_cvt_pk_fp8_f32(a, b, 0u, false);
    r = __builtin_amdgcn_cvt_pk_fp8_f32(c, d, r, true);
    return r;
#else
    union { unsigned char b[4]; unsigned int u; } t;
    t.b[0] = __hip_fp8_e4m3(a).__x; t.b[1] = __hip_fp8_e4m3(b).__x;
    t.b[2] = __hip_fp8_e4m3(c).__x; t.b[3] = __hip_fp8_e4m3(d).__x;
    return t.u;
#endif
}

__device__ __forceinline__ void acc_fp8x4(unsigned int v, float4& a) {
#ifdef FP8_HW
    f32x2 lo = __builtin_amdgcn_cvt_pk_f32_fp8(v, false);
    f32x2 hi = __builtin_amdgcn_cvt_pk_f32_fp8(v, true);
    a.x += lo[0]; a.y += lo[1]; a.z += hi[0]; a.w += hi[1];
#else
    union { unsigned int u; unsigned char b[4]; } t; t.u = v;
    __hip_fp8_e4m3 e0, e1, e2, e3;
    e0.__x = t.b[0]; e1.__x = t.b[1]; e2.__x = t.b[2]; e3.__x = t.b[3];
    a.x += (float)e0; a.y += (float)e1; a.z += (float)e2; a.w += (float)e3;
#endif
}

// ---------------- Kernel 0: rearrange W -> Wg[512][256] f16 ----------------
// Wg rows 0..255 = self half (W[j][0:256]); rows 256..511 = neigh half.
__global__ void wconv(const float* __restrict__ W, f16_t* __restrict__ Wg) {
    int idx = blockIdx.x * 256 + threadIdx.x;
    int j = idx >> 8, k = idx & 255;
    float v = (j < 256) ? W[j * K2 + k] : W[(j - 256) * K2 + 256 + k];
    Wg[idx] = (f16_t)v;
}

// ---------------- Kernel 1: projections (f16 MFMA, unified balanced tile space) ----------------
// 512 persistent blocks stride a UNIFIED 2345-tile space:
//   tiles [0, 1563):   neigh half, A-row = node r            -> P8 (fp8)
//   tiles [1563, 2345): self half,  A-row = F[node_idx[b]]   -> Pselfb (f16)
// Each block sees ~4.58 tiles in ascending order, so the half-switch happens at
// most ONCE per block -> one conditional wgall reload (16 L2 loads, amortized).
// Both co-resident blocks/CU now carry equal work and finish together — no
// solo-block tail (R20's grid (256,2) left ~3 neigh tiles running without an
// anti-phased partner). Inner structure = verified R13/R20: reg-staged T14
// loads one tile ahead, single cvt at stage, swizzled f16 LDS (g ^ (row&7)),
// pure ds_read_b128+MFMA k-loop vs wgall[8][2], one __syncthreads per tile.
__global__ __launch_bounds__(512, 2) void proj_gemm(
    const float* __restrict__ features, const f16_t* __restrict__ Wg,
    const int* __restrict__ node_idx,
    f16_t* __restrict__ Pselfb, unsigned char* __restrict__ Pneigh8)
{
    __shared__ unsigned short buf[2][64 * 256];   // 2 x 32 KB f16 (bits)
    const int tid = threadIdx.x, lane = tid & 63, w = tid >> 6;   // w: 0..7
    const int q16 = lane >> 4, r16 = lane & 15;
    const int row_s = tid >> 3;                   // staging row (0..63)
    const int seg_s = tid & 7;                    // staging segment (32 f32 each)

    f16x8 wgall[8][2];
    // H: 0 = neigh (Wg rows 256..511), 1 = self (Wg rows 0..255)
#define LOADWG(H)                                                               \
    {                                                                           \
        const int c0_ = ((H) ? 0 : 256) + w * 32;                               \
        _Pragma("unroll")                                                       \
        for (int s_ = 0; s_ < 8; ++s_)                                          \
            _Pragma("unroll")                                                   \
            for (int ct_ = 0; ct_ < 2; ++ct_)                                   \
                wgall[s_][ct_] = *(const f16x8*)                                \
                    &Wg[(long)(c0_ + ct_ * 16 + r16) * 256 + s_ * 32 + q16 * 8]; \
    }

    f32x4 acc[2][4];
    #pragma unroll
    for (int ct = 0; ct < 2; ++ct)
        #pragma unroll
        for (int rt = 0; rt < 4; ++rt) acc[ct][rt] = (f32x4){0.f, 0.f, 0.f, 0.f};

    float4 v[8];   // staged fp32 (32 consecutive cols of one row)

#define VLOAD(TT)                                                               \
    {                                                                           \
        long sr_;                                                               \
        if ((TT) >= NTILE_N) {                                                  \
            long b_ = (long)((TT) - NTILE_N) * 64 + row_s;                      \
            if (b_ > BATCH - 1) b_ = BATCH - 1;                                 \
            sr_ = (long)node_idx[b_];                                           \
        } else {                                                                \
            sr_ = (long)(TT) * 64 + row_s;                                      \
            if (sr_ > N_NODES - 1) sr_ = N_NODES - 1;                           \
        }                                                                       \
        const float* p_ = &features[sr_ * IN_F + seg_s * 32];                   \
        _Pragma("unroll")                                                       \
        for (int j_ = 0; j_ < 8; ++j_) v[j_] = *(const float4*)(p_ + j_ * 4);   \
    }

    int curhalf = (blockIdx.x >= NTILE_N) ? 1 : 0;
    LOADWG(curhalf);
    VLOAD(blockIdx.x);
    int cur = 0;

    for (int t = blockIdx.x; t < NTILE_T; t += NBLK) {
        const int th = (t >= NTILE_N) ? 1 : 0;
        if (th != curhalf) { curhalf = th; LOADWG(th); }   // at most once per block

        // ---- cvt + swizzled ds_write (consumes v -> compiler waits exactly here) ----
        #pragma unroll
        for (int p = 0; p < 4; ++p) {
            const int g  = seg_s * 4 + p;              // logical 16B granule (0..31)
            const int gp = g ^ (row_s & 7);            // swizzled position
            f16x8 hh;
            hh[0] = (f16_t)v[2 * p].x;     hh[1] = (f16_t)v[2 * p].y;
            hh[2] = (f16_t)v[2 * p].z;     hh[3] = (f16_t)v[2 * p].w;
            hh[4] = (f16_t)v[2 * p + 1].x; hh[5] = (f16_t)v[2 * p + 1].y;
            hh[6] = (f16_t)v[2 * p + 1].z; hh[7] = (f16_t)v[2 * p + 1].w;
            *(f16x8*)&buf[cur][row_s * 256 + gp * 8] = hh;
        }
        __syncthreads();            // drains only epilogue stores; loads already consumed

        if (t + NBLK < NTILE_T) VLOAD(t + NBLK);   // T14: issue next tile's loads now

        // ---- compute: pure ds_read_b128 -> MFMA ----
        #pragma unroll
        for (int sg = 0; sg < 8; ++sg) {
            f16x8 bfr[4];
            #pragma unroll
            for (int rt = 0; rt < 4; ++rt) {
                const int row = rt * 16 + r16;
                const int g   = (sg * 4 + q16) ^ (row & 7);
                bfr[rt] = *(const f16x8*)&buf[cur][row * 256 + g * 8];
            }
            #pragma unroll
            for (int ct = 0; ct < 2; ++ct)
                #pragma unroll
                for (int rt = 0; rt < 4; ++rt)
                    acc[ct][rt] = __builtin_amdgcn_mfma_f32_16x16x32_f16(
                        wgall[sg][ct], bfr[rt], acc[ct][rt], 0, 0, 0);
        }

        // ---- epilogue for tile t ----
        if (th == 0) {
            const long gr0 = (long)t * 64;
            #pragma unroll
            for (int rt = 0; rt < 4; ++rt) {
                const long row = gr0 + rt * 16 + r16;
                const bool ok = row < N_NODES;
                #pragma unroll
                for (int ct = 0; ct < 2; ++ct) {
                    const int colb = w * 32 + ct * 16 + q16 * 4;
                    unsigned int pk = pk_fp8x4(acc[ct][rt][0], acc[ct][rt][1],
                                               acc[ct][rt][2], acc[ct][rt][3]);
                    if (ok) *(unsigned int*)&Pneigh8[row * 256 + colb] = pk;
                }
            }
        } else {
            const long gr0 = (long)(t - NTILE_N) * 64;
            #pragma unroll
            for (int rt = 0; rt < 4; ++rt) {
                const long b = gr0 + rt * 16 + r16;
                const bool ok = b < BATCH;
                #pragma unroll
                for (int ct = 0; ct < 2; ++ct) {
                    const int colb = w * 32 + ct * 16 + q16 * 4;
                    if (ok) {
                        union { ushort4 u; f16_t hh[4]; } tt;
                        tt.hh[0] = (f16_t)acc[ct][rt][0]; tt.hh[1] = (f16_t)acc[ct][rt][1];
                        tt.hh[2] = (f16_t)acc[ct][rt][2]; tt.hh[3] = (f16_t)acc[ct][rt][3];
                        *(ushort4*)&Pselfb[b * 256 + colb] = tt.u;
                    }
                }
            }
        }
        #pragma unroll
        for (int ct = 0; ct < 2; ++ct)
            #pragma unroll
            for (int rt = 0; rt < 4; ++rt) acc[ct][rt] = (f32x4){0.f, 0.f, 0.f, 0.f};
        cur ^= 1;
    }
#undef VLOAD
#undef LOADWG
}

// ---------------- Kernel 2: out[b] = Pselfb[b] + mean_s fp8(Pneigh[nb[b,s]]) ----------------
__global__ __launch_bounds__(256) void gather_add(
    const f16_t* __restrict__ Pselfb, const unsigned char* __restrict__ P8,
    const int* __restrict__ neigh_idx, float* __restrict__ out)
{
    const int tid = threadIdx.x, lane = tid & 63, w = tid >> 6;
    const long b0 = (long)blockIdx.x * 8 + w * 2;
    const int c4 = lane * 4;

    int ns0[NSAMP], ns1[NSAMP];
    #pragma unroll
    for (int s = 0; s < NSAMP; ++s) ns0[s] = neigh_idx[b0 * NSAMP + s];
    #pragma unroll
    for (int s = 0; s < NSAMP; ++s) ns1[s] = neigh_idx[(b0 + 1) * NSAMP + s];

    const ushort4 sv0 = *(const ushort4*)&Pselfb[b0 * 256 + c4];
    const ushort4 sv1 = *(const ushort4*)&Pselfb[(b0 + 1) * 256 + c4];

    unsigned int v0[NSAMP], v1[NSAMP];
    #pragma unroll
    for (int s = 0; s < NSAMP; ++s)
        v0[s] = *(const unsigned int*)&P8[(long)ns0[s] * 256 + c4];
    #pragma unroll
    for (int s = 0; s < NSAMP; ++s)
        v1[s] = *(const unsigned int*)&P8[(long)ns1[s] * 256 + c4];

    float4 a0 = make_float4(0.f, 0.f, 0.f, 0.f);
    float4 a1 = make_float4(0.f, 0.f, 0.f, 0.f);
    #pragma unroll
    for (int s = 0; s < NSAMP; ++s) acc_fp8x4(v0[s], a0);
    #pragma unroll
    for (int s = 0; s < NSAMP; ++s) acc_fp8x4(v1[s], a1);

    const float inv = 1.0f / (float)NSAMP;
    float4 o0, o1;
    o0.x = h2f(sv0.x) + a0.x * inv; o0.y = h2f(sv0.y) + a0.y * inv;
    o0.z = h2f(sv0.z) + a0.z * inv; o0.w = h2f(sv0.w) + a0.w * inv;
    o1.x = h2f(sv1.x) + a1.x * inv; o1.y = h2f(sv1.y) + a1.y * inv;
    o1.z = h2f(sv1.z) + a1.z * inv; o1.w = h2f(sv1.w) + a1.w * inv;
    *(float4*)&out[b0 * OUT_F + c4] = o0;
    *(float4*)&out[(b0 + 1) * OUT_F + c4] = o1;
}

// ---------------- Fallback (monolithic) if ws too small ----------------
__device__ __forceinline__ int swz_bf(int row, int us_idx) {
    return us_idx ^ ((row & 7) << 3);
}
__device__ __forceinline__ void store_bf4(unsigned short* comb, int r, int col, float4 f) {
    union { ushort4 u; bf16_t b[4]; } t;
    t.b[0] = (bf16_t)f.x; t.b[1] = (bf16_t)f.y;
    t.b[2] = (bf16_t)f.z; t.b[3] = (bf16_t)f.w;
    *(ushort4*)&comb[swz_bf(r, r * K2 + col)] = t.u;
}
__global__ __launch_bounds__(256, 4) void sage_fused(
    const float* __restrict__ features, const int* __restrict__ node_idx,
    const int* __restrict__ neigh_idx, const float* __restrict__ W,
    float* __restrict__ out)
{
    __shared__ unsigned short comb[16 * K2];
    const int tid = threadIdx.x, lane = tid & 63, wy = tid >> 6;
    const int b0 = blockIdx.x * 16;
    const int col4 = lane * 4;
    #pragma unroll
    for (int i = 0; i < 4; ++i) {
        const int r = wy * 4 + i;
        const long b = b0 + r;
        int nidx[NSAMP];
        #pragma unroll
        for (int s = 0; s < NSAMP; ++s) nidx[s] = neigh_idx[b * NSAMP + s];
        const int self_n = node_idx[b];
        const float4 sf = *(const float4*)&features[(long)self_n * IN_F + col4];
        float4 v[13];
        #pragma unroll
        for (int s = 0; s < 13; ++s)
            v[s] = *(const float4*)&features[(long)nidx[s] * IN_F + col4];
        float4 acc = v[0];
        #pragma unroll
        for (int s = 1; s < 13; ++s) {
            acc.x += v[s].x; acc.y += v[s].y; acc.z += v[s].z; acc.w += v[s].w;
        }
        #pragma unroll
        for (int s = 13; s < NSAMP; ++s)
            v[s - 13] = *(const float4*)&features[(long)nidx[s] * IN_F + col4];
        #pragma unroll
        for (int s = 0; s < 12; ++s) {
            acc.x += v[s].x; acc.y += v[s].y; acc.z += v[s].z; acc.w += v[s].w;
        }
        const float inv = 1.0f / (float)NSAMP;
        acc.x *= inv; acc.y *= inv; acc.z *= inv; acc.w *= inv;
        store_bf4(comb, r, col4, sf);
        store_bf4(comb, r, IN_F + col4, acc);
    }
    __syncthreads();
    const int c0 = wy * 64, arow = lane & 15, kq = (lane >> 4) * 8;
    f32x4 acc[4];
    #pragma unroll
    for (int t = 0; t < 4; ++t) acc[t] = (f32x4){0.f, 0.f, 0.f, 0.f};
    #pragma unroll
    for (int ks = 0; ks < 16; ++ks) {
        const int kb = ks * 32 + kq;
        const bf16x8 af = *(const bf16x8*)&comb[swz_bf(arow, arow * K2 + kb)];
        #pragma unroll
        for (int t = 0; t < 4; ++t) {
            const float* wp = &W[(long)(c0 + t * 16 + arow) * K2 + kb];
            const float4 w0 = *(const float4*)wp;
            const float4 w1 = *(const float4*)(wp + 4);
            bf16x8 bf;
            bf[0] = (bf16_t)w0.x; bf[1] = (bf16_t)w0.y;
            bf[2] = (bf16_t)w0.z; bf[3] = (bf16_t)w0.w;
            bf[4] = (bf16_t)w1.x; bf[5] = (bf16_t)w1.y;
            bf[6] = (bf16_t)w1.z; bf[7] = (bf16_t)w1.w;
            acc[t] = __builtin_amdgcn_mfma_f32_16x16x32_bf16(af, bf, acc[t], 0, 0, 0);
        }
    }
    #pragma unroll
    for (int t = 0; t < 4; ++t) {
        const int col = c0 + t * 16 + arow;
        #pragma unroll
        for (int j = 0; j < 4; ++j) {
            const int row = b0 + (lane >> 4) * 4 + j;
            out[(long)row * OUT_F + col] = acc[t][j];
        }
    }
}

extern "C" void kernel_launch(void* const* d_in, const int* in_sizes, int n_in,
                              void* d_out, int out_size, void* d_ws, size_t ws_size,
                              hipStream_t stream) {
    const float* features  = (const float*)d_in[0];
    const int*   node_idx  = (const int*)d_in[1];
    const int*   neigh_idx = (const int*)d_in[2];
    const float* W         = (const float*)d_in[3];
    float*       out       = (float*)d_out;

    if (ws_size >= (size_t)WS_NEED) {
        f16_t*         Pselfb = (f16_t*)d_ws;
        unsigned char* P8     = (unsigned char*)d_ws + P8_OFF;
        f16_t*         Wg     = (f16_t*)((char*)d_ws + WG_OFF);
        wconv<<<512, 256, 0, stream>>>(W, Wg);
        proj_gemm<<<NBLK, 512, 0, stream>>>(features, Wg, node_idx, Pselfb, P8);
        gather_add<<<BATCH / 8, 256, 0, stream>>>(Pselfb, P8, neigh_idx, out);
    } else {
        sage_fused<<<BATCH / 16, 256, 0, stream>>>(features, node_idx, neigh_idx, W, out);
    }
}

// Round 22
// 112.018 us; speedup vs baseline: 1.0884x; 1.0884x over previous
//
#include <hip/hip_runtime.h>

#define N_NODES 100000
#define IN_F    256
#define OUT_F   256
#define BATCH   50000
#define NSAMP   25
#define K2      512
#define NTILE_N 1563    // neigh half: ceil(100000/64), per-node
#define NTILE_B 782     // self half:  ceil(50000/64), per-batch-row
#define NB_NEIGH 342    // blocks for neigh half (1563/342 = 4.57 tiles/block)
#define NB_SELF  170    // blocks for self half  (782/170  = 4.60 tiles/block)
#define NBLK    (NB_NEIGH + NB_SELF)   // 512 total, 2/CU

typedef _Float16 f16_t;
typedef f16_t f16x8 __attribute__((ext_vector_type(8)));
typedef float f32x4 __attribute__((ext_vector_type(4)));
typedef float f32x2 __attribute__((ext_vector_type(2)));
typedef __bf16 bf16_t;
typedef bf16_t bf16x8 __attribute__((ext_vector_type(8)));

#if defined(__has_builtin)
#if __has_builtin(__builtin_amdgcn_cvt_pk_f32_fp8) && __has_builtin(__builtin_amdgcn_cvt_pk_fp8_f32)
#define FP8_HW 1
#endif
#endif
#ifndef FP8_HW
#include <hip/hip_fp8.h>
#endif

// workspace (bytes): Pselfb f16 [50000][256] (batch-indexed), P8 fp8 [100000][256], Wg f16 [512][256]
#define P8_OFF   25600000L
#define WG_OFF   51200000L
#define WS_NEED  (WG_OFF + 512L * 256 * 2)

__device__ __forceinline__ float h2f(unsigned short u) {
    union { unsigned short u; f16_t h; } t; t.u = u; return (float)t.h;
}

__device__ __forceinline__ unsigned int pk_fp8x4(float a, float b, float c, float d) {
#ifdef FP8_HW
    unsigned int r = __builtin_amdgcn_cvt_pk_fp8_f32(a, b, 0u, false);
    r = __builtin_amdgcn_cvt_pk_fp8_f32(c, d, r, true);
    return r;
#else
    union { unsigned char b[4]; unsigned int u; } t;
    t.b[0] = __hip_fp8_e4m3(a).__x; t.b[1] = __hip_fp8_e4m3(b).__x;
    t.b[2] = __hip_fp8_e4m3(c).__x; t.b[3] = __hip_fp8_e4m3(d).__x;
    return t.u;
#endif
}

__device__ __forceinline__ void acc_fp8x4(unsigned int v, float4& a) {
#ifdef FP8_HW
    f32x2 lo = __builtin_amdgcn_cvt_pk_f32_fp8(v, false);
    f32x2 hi = __builtin_amdgcn_cvt_pk_f32_fp8(v, true);
    a.x += lo[0]; a.y += lo[1]; a.z += hi[0]; a.w += hi[1];
#else
    union { unsigned int u; unsigned char b[4]; } t; t.u = v;
    __hip_fp8_e4m3 e0, e1, e2, e3;
    e0.__x = t.b[0]; e1.__x = t.b[1]; e2.__x = t.b[2]; e3.__x = t.b[3];
    a.x += (float)e0; a.y += (float)e1; a.z += (float)e2; a.w += (float)e3;
#endif
}

// ---------------- Kernel 0: rearrange W -> Wg[512][256] f16 ----------------
// Wg rows 0..255 = self half (W[j][0:256]); rows 256..511 = neigh half.
__global__ void wconv(const float* __restrict__ W, f16_t* __restrict__ Wg) {
    int idx = blockIdx.x * 256 + threadIdx.x;
    int j = idx >> 8, k = idx & 255;
    float v = (j < 256) ? W[j * K2 + k] : W[(j - 256) * K2 + 256 + k];
    Wg[idx] = (f16_t)v;
}

// ---------------- Kernel 1: projections (f16 MFMA, work-proportional block split) ----------------
// 512 persistent blocks, block-uniform half selection (NO per-tile branching):
//   blocks [0, 342):   neigh half, 1563 tiles stride 342 -> P8 (fp8, per-node)
//   blocks [342, 512): self half,   782 tiles stride 170 -> Pselfb (f16, per-batch)
// Each block carries ~4.6 tiles (R20's split was 6.1 / 3.05, leaving a ~3-tile
// solo-block tail per CU). Inner loop is the VERIFIED R13/R20 structure,
// compile-time specialized per half via template<H>: reg-staged T14 loads one
// tile ahead, single cvt at stage, swizzled f16 LDS (granule g ^ (row&7)),
// pure ds_read_b128+MFMA k-loop vs wgall[8][2], one __syncthreads per tile.
template <int H>   // 0 = neigh, 1 = self
__device__ __forceinline__ void proj_run(
    const float* __restrict__ features, const f16_t* __restrict__ Wg,
    const int* __restrict__ node_idx,
    f16_t* __restrict__ Pselfb, unsigned char* __restrict__ Pneigh8,
    unsigned short (*buf)[64 * 256], const int bid0)
{
    const int ntile = (H == 0) ? NTILE_N : NTILE_B;
    const int nblk  = (H == 0) ? NB_NEIGH : NB_SELF;
    const int rmax  = (H == 0) ? N_NODES : BATCH;

    const int tid = threadIdx.x, lane = tid & 63, w = tid >> 6;   // w: 0..7
    const int q16 = lane >> 4, r16 = lane & 15;
    const int c0 = (H == 0 ? 256 : 0) + w * 32;   // Wg col base for this wave
    const int row_s = tid >> 3;                   // staging row (0..63)
    const int seg_s = tid & 7;                    // staging segment (32 f32 each)

    // ---- hoist the wave's Wg slice: 8 k-steps x 2 col-frags = 64 VGPR ----
    f16x8 wgall[8][2];
    #pragma unroll
    for (int s = 0; s < 8; ++s)
        #pragma unroll
        for (int ct = 0; ct < 2; ++ct)
            wgall[s][ct] = *(const f16x8*)&Wg[(long)(c0 + ct * 16 + r16) * 256 + s * 32 + q16 * 8];

    f32x4 acc[2][4];
    #pragma unroll
    for (int ct = 0; ct < 2; ++ct)
        #pragma unroll
        for (int rt = 0; rt < 4; ++rt) acc[ct][rt] = (f32x4){0.f, 0.f, 0.f, 0.f};

    float4 v[8];   // staged fp32 (32 consecutive cols of one row)

#define VLOAD(TT)                                                               \
    {                                                                           \
        long rr_ = (long)(TT) * 64 + row_s;                                     \
        if (rr_ > rmax - 1) rr_ = rmax - 1;                                     \
        const long sr_ = (H == 0) ? rr_ : (long)node_idx[rr_];                  \
        const float* p_ = &features[sr_ * IN_F + seg_s * 32];                   \
        _Pragma("unroll")                                                       \
        for (int j_ = 0; j_ < 8; ++j_) v[j_] = *(const float4*)(p_ + j_ * 4);   \
    }

    VLOAD(bid0);
    int cur = 0;

    for (int t = bid0; t < ntile; t += nblk) {
        // ---- cvt + swizzled ds_write (consumes v -> compiler waits exactly here) ----
        #pragma unroll
        for (int p = 0; p < 4; ++p) {
            const int g  = seg_s * 4 + p;              // logical 16B granule (0..31)
            const int gp = g ^ (row_s & 7);            // swizzled position
            f16x8 hh;
            hh[0] = (f16_t)v[2 * p].x;     hh[1] = (f16_t)v[2 * p].y;
            hh[2] = (f16_t)v[2 * p].z;     hh[3] = (f16_t)v[2 * p].w;
            hh[4] = (f16_t)v[2 * p + 1].x; hh[5] = (f16_t)v[2 * p + 1].y;
            hh[6] = (f16_t)v[2 * p + 1].z; hh[7] = (f16_t)v[2 * p + 1].w;
            *(f16x8*)&buf[cur][row_s * 256 + gp * 8] = hh;
        }
        __syncthreads();            // drains only epilogue stores; loads already consumed

        if (t + nblk < ntile) VLOAD(t + nblk);   // T14: issue next tile's loads now

        // ---- compute: pure ds_read_b128 -> MFMA ----
        #pragma unroll
        for (int sg = 0; sg < 8; ++sg) {
            f16x8 bfr[4];
            #pragma unroll
            for (int rt = 0; rt < 4; ++rt) {
                const int row = rt * 16 + r16;
                const int g   = (sg * 4 + q16) ^ (row & 7);
                bfr[rt] = *(const f16x8*)&buf[cur][row * 256 + g * 8];
            }
            #pragma unroll
            for (int ct = 0; ct < 2; ++ct)
                #pragma unroll
                for (int rt = 0; rt < 4; ++rt)
                    acc[ct][rt] = __builtin_amdgcn_mfma_f32_16x16x32_f16(
                        wgall[sg][ct], bfr[rt], acc[ct][rt], 0, 0, 0);
        }

        // ---- epilogue for tile t (compile-time per half) ----
        const long gr0 = (long)t * 64;
        if (H == 0) {
            #pragma unroll
            for (int rt = 0; rt < 4; ++rt) {
                const long row = gr0 + rt * 16 + r16;
                const bool ok = row < N_NODES;
                #pragma unroll
                for (int ct = 0; ct < 2; ++ct) {
                    const int colb = w * 32 + ct * 16 + q16 * 4;
                    unsigned int pk = pk_fp8x4(acc[ct][rt][0], acc[ct][rt][1],
                                               acc[ct][rt][2], acc[ct][rt][3]);
                    if (ok) *(unsigned int*)&Pneigh8[row * 256 + colb] = pk;
                }
            }
        } else {
            #pragma unroll
            for (int rt = 0; rt < 4; ++rt) {
                const long b = gr0 + rt * 16 + r16;
                const bool ok = b < BATCH;
                #pragma unroll
                for (int ct = 0; ct < 2; ++ct) {
                    const int colb = w * 32 + ct * 16 + q16 * 4;
                    if (ok) {
                        union { ushort4 u; f16_t hh[4]; } tt;
                        tt.hh[0] = (f16_t)acc[ct][rt][0]; tt.hh[1] = (f16_t)acc[ct][rt][1];
                        tt.hh[2] = (f16_t)acc[ct][rt][2]; tt.hh[3] = (f16_t)acc[ct][rt][3];
                        *(ushort4*)&Pselfb[b * 256 + colb] = tt.u;
                    }
                }
            }
        }
        #pragma unroll
        for (int ct = 0; ct < 2; ++ct)
            #pragma unroll
            for (int rt = 0; rt < 4; ++rt) acc[ct][rt] = (f32x4){0.f, 0.f, 0.f, 0.f};
        cur ^= 1;
    }
#undef VLOAD
}

__global__ __launch_bounds__(512, 2) void proj_gemm(
    const float* __restrict__ features, const f16_t* __restrict__ Wg,
    const int* __restrict__ node_idx,
    f16_t* __restrict__ Pselfb, unsigned char* __restrict__ Pneigh8)
{
    __shared__ unsigned short buf[2][64 * 256];   // 2 x 32 KB f16 (bits)
    if (blockIdx.x < NB_NEIGH)
        proj_run<0>(features, Wg, node_idx, Pselfb, Pneigh8, buf, blockIdx.x);
    else
        proj_run<1>(features, Wg, node_idx, Pselfb, Pneigh8, buf, blockIdx.x - NB_NEIGH);
}

// ---------------- Kernel 2: out[b] = Pselfb[b] + mean_s fp8(Pneigh[nb[b,s]]) ----------------
__global__ __launch_bounds__(256) void gather_add(
    const f16_t* __restrict__ Pselfb, const unsigned char* __restrict__ P8,
    const int* __restrict__ neigh_idx, float* __restrict__ out)
{
    const int tid = threadIdx.x, lane = tid & 63, w = tid >> 6;
    const long b0 = (long)blockIdx.x * 8 + w * 2;
    const int c4 = lane * 4;

    int ns0[NSAMP], ns1[NSAMP];
    #pragma unroll
    for (int s = 0; s < NSAMP; ++s) ns0[s] = neigh_idx[b0 * NSAMP + s];
    #pragma unroll
    for (int s = 0; s < NSAMP; ++s) ns1[s] = neigh_idx[(b0 + 1) * NSAMP + s];

    const ushort4 sv0 = *(const ushort4*)&Pselfb[b0 * 256 + c4];
    const ushort4 sv1 = *(const ushort4*)&Pselfb[(b0 + 1) * 256 + c4];

    unsigned int v0[NSAMP], v1[NSAMP];
    #pragma unroll
    for (int s = 0; s < NSAMP; ++s)
        v0[s] = *(const unsigned int*)&P8[(long)ns0[s] * 256 + c4];
    #pragma unroll
    for (int s = 0; s < NSAMP; ++s)
        v1[s] = *(const unsigned int*)&P8[(long)ns1[s] * 256 + c4];

    float4 a0 = make_float4(0.f, 0.f, 0.f, 0.f);
    float4 a1 = make_float4(0.f, 0.f, 0.f, 0.f);
    #pragma unroll
    for (int s = 0; s < NSAMP; ++s) acc_fp8x4(v0[s], a0);
    #pragma unroll
    for (int s = 0; s < NSAMP; ++s) acc_fp8x4(v1[s], a1);

    const float inv = 1.0f / (float)NSAMP;
    float4 o0, o1;
    o0.x = h2f(sv0.x) + a0.x * inv; o0.y = h2f(sv0.y) + a0.y * inv;
    o0.z = h2f(sv0.z) + a0.z * inv; o0.w = h2f(sv0.w) + a0.w * inv;
    o1.x = h2f(sv1.x) + a1.x * inv; o1.y = h2f(sv1.y) + a1.y * inv;
    o1.z = h2f(sv1.z) + a1.z * inv; o1.w = h2f(sv1.w) + a1.w * inv;
    *(float4*)&out[b0 * OUT_F + c4] = o0;
    *(float4*)&out[(b0 + 1) * OUT_F + c4] = o1;
}

// ---------------- Fallback (monolithic) if ws too small ----------------
__device__ __forceinline__ int swz_bf(int row, int us_idx) {
    return us_idx ^ ((row & 7) << 3);
}
__device__ __forceinline__ void store_bf4(unsigned short* comb, int r, int col, float4 f) {
    union { ushort4 u; bf16_t b[4]; } t;
    t.b[0] = (bf16_t)f.x; t.b[1] = (bf16_t)f.y;
    t.b[2] = (bf16_t)f.z; t.b[3] = (bf16_t)f.w;
    *(ushort4*)&comb[swz_bf(r, r * K2 + col)] = t.u;
}
__global__ __launch_bounds__(256, 4) void sage_fused(
    const float* __restrict__ features, const int* __restrict__ node_idx,
    const int* __restrict__ neigh_idx, const float* __restrict__ W,
    float* __restrict__ out)
{
    __shared__ unsigned short comb[16 * K2];
    const int tid = threadIdx.x, lane = tid & 63, wy = tid >> 6;
    const int b0 = blockIdx.x * 16;
    const int col4 = lane * 4;
    #pragma unroll
    for (int i = 0; i < 4; ++i) {
        const int r = wy * 4 + i;
        const long b = b0 + r;
        int nidx[NSAMP];
        #pragma unroll
        for (int s = 0; s < NSAMP; ++s) nidx[s] = neigh_idx[b * NSAMP + s];
        const int self_n = node_idx[b];
        const float4 sf = *(const float4*)&features[(long)self_n * IN_F + col4];
        float4 v[13];
        #pragma unroll
        for (int s = 0; s < 13; ++s)
            v[s] = *(const float4*)&features[(long)nidx[s] * IN_F + col4];
        float4 acc = v[0];
        #pragma unroll
        for (int s = 1; s < 13; ++s) {
            acc.x += v[s].x; acc.y += v[s].y; acc.z += v[s].z; acc.w += v[s].w;
        }
        #pragma unroll
        for (int s = 13; s < NSAMP; ++s)
            v[s - 13] = *(const float4*)&features[(long)nidx[s] * IN_F + col4];
        #pragma unroll
        for (int s = 0; s < 12; ++s) {
            acc.x += v[s].x; acc.y += v[s].y; acc.z += v[s].z; acc.w += v[s].w;
        }
        const float inv = 1.0f / (float)NSAMP;
        acc.x *= inv; acc.y *= inv; acc.z *= inv; acc.w *= inv;
        store_bf4(comb, r, col4, sf);
        store_bf4(comb, r, IN_F + col4, acc);
    }
    __syncthreads();
    const int c0 = wy * 64, arow = lane & 15, kq = (lane >> 4) * 8;
    f32x4 acc[4];
    #pragma unroll
    for (int t = 0; t < 4; ++t) acc[t] = (f32x4){0.f, 0.f, 0.f, 0.f};
    #pragma unroll
    for (int ks = 0; ks < 16; ++ks) {
        const int kb = ks * 32 + kq;
        const bf16x8 af = *(const bf16x8*)&comb[swz_bf(arow, arow * K2 + kb)];
        #pragma unroll
        for (int t = 0; t < 4; ++t) {
            const float* wp = &W[(long)(c0 + t * 16 + arow) * K2 + kb];
            const float4 w0 = *(const float4*)wp;
            const float4 w1 = *(const float4*)(wp + 4);
            bf16x8 bf;
            bf[0] = (bf16_t)w0.x; bf[1] = (bf16_t)w0.y;
            bf[2] = (bf16_t)w0.z; bf[3] = (bf16_t)w0.w;
            bf[4] = (bf16_t)w1.x; bf[5] = (bf16_t)w1.y;
            bf[6] = (bf16_t)w1.z; bf[7] = (bf16_t)w1.w;
            acc[t] = __builtin_amdgcn_mfma_f32_16x16x32_bf16(af, bf, acc[t], 0, 0, 0);
        }
    }
    #pragma unroll
    for (int t = 0; t < 4; ++t) {
        const int col = c0 + t * 16 + arow;
        #pragma unroll
        for (int j = 0; j < 4; ++j) {
            const int row = b0 + (lane >> 4) * 4 + j;
            out[(long)row * OUT_F + col] = acc[t][j];
        }
    }
}

extern "C" void kernel_launch(void* const* d_in, const int* in_sizes, int n_in,
                              void* d_out, int out_size, void* d_ws, size_t ws_size,
                              hipStream_t stream) {
    const float* features  = (const float*)d_in[0];
    const int*   node_idx  = (const int*)d_in[1];
    const int*   neigh_idx = (const int*)d_in[2];
    const float* W         = (const float*)d_in[3];
    float*       out       = (float*)d_out;

    if (ws_size >= (size_t)WS_NEED) {
        f16_t*         Pselfb = (f16_t*)d_ws;
        unsigned char* P8     = (unsigned char*)d_ws + P8_OFF;
        f16_t*         Wg     = (f16_t*)((char*)d_ws + WG_OFF);
        wconv<<<512, 256, 0, stream>>>(W, Wg);
        proj_gemm<<<NBLK, 512, 0, stream>>>(features, Wg, node_idx, Pselfb, P8);
        gather_add<<<BATCH / 8, 256, 0, stream>>>(Pselfb, P8, neigh_idx, out);
    } else {
        sage_fused<<<BATCH / 16, 256, 0, stream>>>(features, node_idx, neigh_idx, W, out);
    }
}